// Round 1
// baseline (1572.840 us; speedup 1.0000x reference)
//
#include <hip/hip_runtime.h>
#include <hip/hip_fp16.h>

// R12: replace the atomic push-scatter (312us; 6.4M memory-side pk_f16
// line-RMWs at ~20.5 G lines/s = calibrated floor, WRITE_SIZE 400MB shows
// full write-through) with a counting sort into 512-vnode buckets + LDS
// fp32 accumulation + one dense f16 flush per bucket. Global fp atomics: 0.
//
// vnode = type*N + node (M = 2N = 200000, fits 18 bits; requires N <= 131072)
// code  = (dst_local << 18) | vsrc   (9 + 18 = 27 bits)
//
// Pipeline:
//  1. bhist   : per-(slice,type) bucket histogram       -> counts[512][nb]
//  2. scanA   : exclusive scan over slices per bucket   -> offsets[512][nb]
//  3. scanB   : exclusive scan over buckets (4-padded)  -> bucket_base[nb+1]
//  4. place   : scatter edge codes into bucket segments (LDS cursors)
//  5. dcount  : per-dst degree from sorted codes -> cnt (replaces old hist
//               kernel AND the memset)
//  6. xw      : xws[v] = (x @ W_type) * rsqrt(deg+1), f16x2 (no acc seed)
//  7. gather  : per bucket: fp32 LDS accumulate, dense f16 flush to acc
//  8. epilogue: out = relu((acc + self)*dinv + b) . W_lin + b_lin

#define SLICES 256
#define G2     (2 * SLICES)   // 512 slice rows (256 per edge type)
#define BSZ    512            // vnodes per bucket
#define BSHIFT 9
#define NB_MAX 400
#define LDSPAD 33             // facc row stride: bank = (dl + 2*sl) & 31 -> <=2-way typical

// ---------------- 1. bucket histogram per (slice, type) ----------------
__global__ __launch_bounds__(256)
void bhist_kernel(const int* __restrict__ ei_n, const int* __restrict__ ei_s,
                  int* __restrict__ counts, int N, int En, int Es, int nb) {
    __shared__ int bh[NB_MAX];
    for (int b = threadIdx.x; b < nb; b += 256) bh[b] = 0;
    __syncthreads();
    const int type = blockIdx.y;
    const int E = type ? Es : En;
    const int* __restrict__ dst = (type ? ei_s + Es : ei_n + En);
    const int vbase = type ? N : 0;
    int per = ((E + SLICES - 1) / SLICES + 3) & ~3;
    const int e0 = blockIdx.x * per;
    const int e1 = min(e0 + per, E);
    int i = e0 + (int)threadIdx.x * 4;
    for (; i + 3 < e1; i += 256 * 4) {
        int4 d4 = *(const int4*)(dst + i);
        atomicAdd(&bh[(vbase + d4.x) >> BSHIFT], 1);
        atomicAdd(&bh[(vbase + d4.y) >> BSHIFT], 1);
        atomicAdd(&bh[(vbase + d4.z) >> BSHIFT], 1);
        atomicAdd(&bh[(vbase + d4.w) >> BSHIFT], 1);
    }
    for (; i < e1; ++i) atomicAdd(&bh[(vbase + dst[i]) >> BSHIFT], 1);
    __syncthreads();
    const int g = type * SLICES + blockIdx.x;
    for (int b = threadIdx.x; b < nb; b += 256) counts[(size_t)g * nb + b] = bh[b];
}

// ---------------- 2. scan over slices, per bucket ----------------
__global__ __launch_bounds__(G2)
void scanA_kernel(const int* __restrict__ counts, int* __restrict__ offsets,
                  int* __restrict__ totals, int nb) {
    __shared__ int s[G2];
    const int b = blockIdx.x;
    const int g = threadIdx.x;
    int c = counts[(size_t)g * nb + b];
    s[g] = c;
    __syncthreads();
    for (int o = 1; o < G2; o <<= 1) {
        int t = (g >= o) ? s[g - o] : 0;
        __syncthreads();
        s[g] += t;
        __syncthreads();
    }
    offsets[(size_t)g * nb + b] = s[g] - c;   // exclusive within bucket
    if (g == G2 - 1) totals[b] = s[g];
}

// ---------------- 3. scan over buckets (bases padded to mult of 4) ----------------
__global__ __launch_bounds__(G2)
void scanB_kernel(const int* __restrict__ totals, int* __restrict__ bucket_base, int nb) {
    __shared__ int s[G2];
    const int g = threadIdx.x;
    int c = (g < nb) ? ((totals[g] + 3) & ~3) : 0;   // pad: keeps uint4 loads aligned
    s[g] = c;
    __syncthreads();
    for (int o = 1; o < G2; o <<= 1) {
        int t = (g >= o) ? s[g - o] : 0;
        __syncthreads();
        s[g] += t;
        __syncthreads();
    }
    if (g < nb) bucket_base[g] = s[g] - c;
    if (g == G2 - 1) bucket_base[nb] = s[g];
}

// ---------------- 4. placement: scatter codes into bucket segments ----------------
__global__ __launch_bounds__(256)
void place_kernel(const int* __restrict__ ei_n, const int* __restrict__ ei_s,
                  const int* __restrict__ offsets, const int* __restrict__ bucket_base,
                  unsigned int* __restrict__ codes, int N, int En, int Es, int nb) {
    __shared__ int cur[NB_MAX];
    const int type = blockIdx.y;
    const int g = type * SLICES + blockIdx.x;
    for (int b = threadIdx.x; b < nb; b += 256)
        cur[b] = offsets[(size_t)g * nb + b] + bucket_base[b];
    __syncthreads();
    const int* __restrict__ ei = type ? ei_s : ei_n;
    const int E = type ? Es : En;
    const int vbase = type ? N : 0;
    int per = ((E + SLICES - 1) / SLICES + 3) & ~3;
    const int e0 = blockIdx.x * per;
    const int e1 = min(e0 + per, E);

#define PLACE(sv, dv) do {                                             \
        int vd = vbase + (dv); int bb = vd >> BSHIFT;                  \
        int pos = atomicAdd(&cur[bb], 1);                              \
        codes[pos] = ((unsigned)(vd & (BSZ - 1)) << 18)                \
                   | (unsigned)(vbase + (sv));                         \
    } while (0)

    int i = e0 + (int)threadIdx.x * 4;
    for (; i + 3 < e1; i += 256 * 4) {
        int4 s4 = *(const int4*)(ei + i);
        int4 d4 = *(const int4*)(ei + E + i);
        PLACE(s4.x, d4.x);
        PLACE(s4.y, d4.y);
        PLACE(s4.z, d4.z);
        PLACE(s4.w, d4.w);
    }
    for (; i < e1; ++i) PLACE(ei[i], ei[E + i]);
#undef PLACE
}

// ---------------- 5. per-dst degree from sorted codes ----------------
__global__ __launch_bounds__(512)
void dcount_kernel(const unsigned int* __restrict__ codes, const int* __restrict__ bucket_base,
                   const int* __restrict__ totals, int* __restrict__ cnt, int M) {
    __shared__ int dcnt[BSZ];
    dcnt[threadIdx.x] = 0;
    __syncthreads();
    const int b = blockIdx.x;
    const int base = bucket_base[b];
    const int end = base + totals[b];
    for (int e = base + (int)threadIdx.x; e < end; e += 512)
        atomicAdd(&dcnt[codes[e] >> 18], 1);
    __syncthreads();
    const int vnode = b * BSZ + (int)threadIdx.x;
    if (vnode < M) cnt[vnode] = dcnt[threadIdx.x];
}

// ---------------- 6. xws[type][node] = (x @ W) * rsqrt(deg+1), __half2 ----------------
__global__ void xw_kernel(const float* __restrict__ x,
                          const float* __restrict__ Wn, const float* __restrict__ Ws,
                          const int* __restrict__ cnt,
                          __half2* __restrict__ xws, int N) {
    __shared__ float wn[64 * 32];
    __shared__ float wsm[64 * 32];
    for (int i = threadIdx.x; i < 64 * 32; i += blockDim.x) {
        wn[i] = Wn[i];
        wsm[i] = Ws[i];
    }
    __syncthreads();
    int lane = threadIdx.x & 31;
    int node = blockIdx.x * (blockDim.x >> 5) + (threadIdx.x >> 5);
    if (node >= N) return;

    const float4* x4 = (const float4*)(x + (size_t)node * 64);
    float an = 0.f, as = 0.f;
#pragma unroll
    for (int k4 = 0; k4 < 16; ++k4) {
        float4 xv = x4[k4];
        int k = k4 * 4;
        an += xv.x * wn[(k + 0) * 32 + lane] + xv.y * wn[(k + 1) * 32 + lane]
            + xv.z * wn[(k + 2) * 32 + lane] + xv.w * wn[(k + 3) * 32 + lane];
        as += xv.x * wsm[(k + 0) * 32 + lane] + xv.y * wsm[(k + 1) * 32 + lane]
            + xv.z * wsm[(k + 2) * 32 + lane] + xv.w * wsm[(k + 3) * 32 + lane];
    }
    float vn = an * rsqrtf((float)cnt[node] + 1.0f);
    float vs = as * rsqrtf((float)cnt[N + node] + 1.0f);
    int sl = lane & 15;
    float vn0 = __shfl(vn, 2 * sl, 32);
    float vn1 = __shfl(vn, 2 * sl + 1, 32);
    float vs0 = __shfl(vs, 2 * sl, 32);
    float vs1 = __shfl(vs, 2 * sl + 1, 32);
    if (lane < 16) {
        xws[(size_t)node * 16 + sl] = __floats2half2_rn(vn0, vn1);
        xws[((size_t)N + node) * 16 + sl] = __floats2half2_rn(vs0, vs1);
    }
}

// ---------------- 7. per-bucket fp32 LDS accumulate + dense flush ----------------
__global__ __launch_bounds__(512)
void gather_kernel(const unsigned int* __restrict__ codes, const int* __restrict__ bucket_base,
                   const int* __restrict__ totals, const __half2* __restrict__ xws,
                   __half2* __restrict__ acc, int M) {
    __shared__ float facc[BSZ * LDSPAD];   // 67.6 KB -> 2 blocks/CU
    for (int i = threadIdx.x; i < BSZ * LDSPAD; i += 512) facc[i] = 0.f;
    __syncthreads();
    const int b = blockIdx.x;
    const int base = bucket_base[b];            // multiple of 4 (scanB pad)
    const int end = base + totals[b];
    const int sl = threadIdx.x & 15;
    const int grp = threadIdx.x >> 4;           // 32 groups of 16 lanes

#define ACC_EDGE(cc) do {                                                    \
        unsigned c_ = (cc);                                                  \
        float2 f_ = __half22float2(xws[(size_t)(c_ & 0x3FFFFu) * 16 + sl]);  \
        int r_ = (int)(c_ >> 18) * LDSPAD + 2 * sl;                          \
        atomicAdd(&facc[r_], f_.x);                                          \
        atomicAdd(&facc[r_ + 1], f_.y);                                      \
    } while (0)

    for (int e = base + grp * 4; e + 3 < end; e += 32 * 4) {
        uint4 c4 = *(const uint4*)(codes + e);   // wave: 4 groups = 1 line
        ACC_EDGE(c4.x);
        ACC_EDGE(c4.y);
        ACC_EDGE(c4.z);
        ACC_EDGE(c4.w);
    }
    const int t0 = base + ((end - base) & ~3);
    if (grp < end - t0) ACC_EDGE(codes[t0 + grp]);
#undef ACC_EDGE

    __syncthreads();
    for (int i = threadIdx.x; i < BSZ * 16; i += 512) {
        int dl = i >> 4, s = i & 15;
        int vnode = b * BSZ + dl;
        if (vnode < M)
            acc[(size_t)vnode * 16 + s] =
                __floats2half2_rn(facc[dl * LDSPAD + 2 * s], facc[dl * LDSPAD + 2 * s + 1]);
    }
}

// ---------------- 8. epilogue (adds self-loop term from xws) ----------------
__global__ void epilogue_kernel(const __half2* __restrict__ acc, const __half2* __restrict__ xws,
                                const int* __restrict__ cnt,
                                const float* __restrict__ b_n, const float* __restrict__ b_s,
                                const float* __restrict__ W_lin, const float* __restrict__ b_lin,
                                float* __restrict__ out, int N) {
    int gid = blockIdx.x * blockDim.x + threadIdx.x;
    int node = gid >> 4, sl = gid & 15;
    if (node >= N) return;
    float2 an = __half22float2(acc[(size_t)node * 16 + sl]);
    float2 ns = __half22float2(xws[(size_t)node * 16 + sl]);
    float2 as = __half22float2(acc[((size_t)N + node) * 16 + sl]);
    float2 ss = __half22float2(xws[((size_t)N + node) * 16 + sl]);
    float dn = rsqrtf((float)cnt[node] + 1.0f);
    float dsv = rsqrtf((float)cnt[N + node] + 1.0f);
    float h0 = (an.x + ns.x) * dn + b_n[2 * sl] + (as.x + ss.x) * dsv + b_s[2 * sl];
    float h1 = (an.y + ns.y) * dn + b_n[2 * sl + 1] + (as.y + ss.y) * dsv + b_s[2 * sl + 1];
    float p = fmaxf(h0, 0.f) * W_lin[2 * sl] + fmaxf(h1, 0.f) * W_lin[2 * sl + 1];
#pragma unroll
    for (int off = 8; off > 0; off >>= 1) p += __shfl_xor(p, off, 16);
    if (sl == 0) out[node] = p + b_lin[0];
}

extern "C" void kernel_launch(void* const* d_in, const int* in_sizes, int n_in,
                              void* d_out, int out_size, void* d_ws, size_t ws_size,
                              hipStream_t stream) {
    const float* x     = (const float*)d_in[0];
    const int*   ei_n  = (const int*)d_in[1];
    const int*   ei_s  = (const int*)d_in[2];
    const float* W_n   = (const float*)d_in[3];
    const float* b_n   = (const float*)d_in[4];
    const float* W_s   = (const float*)d_in[5];
    const float* b_s   = (const float*)d_in[6];
    const float* W_lin = (const float*)d_in[7];
    const float* b_lin = (const float*)d_in[8];
    float* out = (float*)d_out;

    const int N  = in_sizes[0] / 64;   // 100000
    const int En = in_sizes[1] / 2;    // 3200000
    const int Es = in_sizes[2] / 2;    // 3200000
    const int M  = 2 * N;              // 200000 vnodes
    const int nb = (M + BSZ - 1) / BSZ;            // 391 buckets
    const size_t Etot = (size_t)En + (size_t)Es;   // 6.4M

    // Workspace layout (~54 MB):
    // cnt[M] | counts[G2*nb] | offsets[G2*nb] | totals[nb] | bucket_base[nb+1]
    // | codes[Etot + 4*nb] (16B aligned) | xws[16*M half2] | acc[16*M half2]
    int* cnt         = (int*)d_ws;
    int* counts      = cnt + M;
    int* offsets     = counts + (size_t)G2 * nb;
    int* totals      = offsets + (size_t)G2 * nb;
    int* bucket_base = totals + nb;
    uintptr_t pcodes = (uintptr_t)(bucket_base + nb + 1);
    pcodes = (pcodes + 15) & ~(uintptr_t)15;
    unsigned int* codes = (unsigned int*)pcodes;
    __half2* xws = (__half2*)(codes + Etot + 4 * (size_t)nb);
    __half2* acc = xws + (size_t)16 * M;

    bhist_kernel<<<dim3(SLICES, 2), 256, 0, stream>>>(ei_n, ei_s, counts, N, En, Es, nb);
    scanA_kernel<<<nb, G2, 0, stream>>>(counts, offsets, totals, nb);
    scanB_kernel<<<1, G2, 0, stream>>>(totals, bucket_base, nb);
    place_kernel<<<dim3(SLICES, 2), 256, 0, stream>>>(ei_n, ei_s, offsets, bucket_base,
                                                      codes, N, En, Es, nb);
    dcount_kernel<<<nb, 512, 0, stream>>>(codes, bucket_base, totals, cnt, M);
    xw_kernel<<<(N + 7) / 8, 256, 0, stream>>>(x, W_n, W_s, cnt, xws, N);
    gather_kernel<<<nb, 512, 0, stream>>>(codes, bucket_base, totals, xws, acc, M);
    epilogue_kernel<<<(int)(((size_t)N * 16 + 255) / 256), 256, 0, stream>>>(
        acc, xws, cnt, b_n, b_s, W_lin, b_lin, out, N);
}

// Round 2
// 379.729 us; speedup vs baseline: 4.1420x; 4.1420x over previous
//
#include <hip/hip_runtime.h>
#include <hip/hip_fp16.h>

// R13: R12's counting-sort + LDS-accumulate gather, with the gather's float
// LDS atomicAdd (compiled to a CAS loop -> 1351us, everything idle) replaced
// by NATIVE integer LDS atomics (ds_add_u32) on fixed-point 2^16 values.
// Also: BSZ 512->256 (33.8KB LDS, 4 blocks/CU, 782 blocks) and 8-edge ILP
// per 16-lane group with loads issued before any LDS atomic.
//
// vnode = type*N + node (M = 2N = 200000, fits 18 bits)
// code  = (dst_local << 18) | vsrc   (8 + 18 = 26 bits)
//
// Pipeline:
//  1. bhist   : per-(slice,type) bucket histogram       -> counts[512][nb]
//  2. scanA   : exclusive scan over slices per bucket   (in-place -> offsets)
//  3. scanB   : exclusive scan over buckets (4-padded)  -> bucket_base[nb]
//  4. place   : scatter edge codes into bucket segments (LDS cursors)
//  5. dcount  : per-dst degree from sorted codes        -> cnt
//  6. xw      : xws[v] = (x @ W_type) * rsqrt(deg+1), f16x2
//  7. gather  : per bucket: int32 fixed-point LDS accumulate, dense f16 flush
//  8. epilogue: out = relu((acc + self)*dinv + b) . W_lin + b_lin

#define SLICES 256
#define G2     (2 * SLICES)   // 512 slice rows (256 per edge type)
#define BSZ    256            // vnodes per bucket
#define BSHIFT 8
#define NB_MAX 800
#define LDSPAD 33             // facc row stride: bank = (dl + 2*sl) & 31 -> <=2-way
#define FXS    65536.0f       // fixed-point scale 2^16
#define FXSI   (1.0f / 65536.0f)

// ---------------- 1. bucket histogram per (slice, type) ----------------
__global__ __launch_bounds__(256)
void bhist_kernel(const int* __restrict__ ei_n, const int* __restrict__ ei_s,
                  int* __restrict__ counts, int N, int En, int Es, int nb) {
    __shared__ int bh[NB_MAX];
    for (int b = threadIdx.x; b < nb; b += 256) bh[b] = 0;
    __syncthreads();
    const int type = blockIdx.y;
    const int E = type ? Es : En;
    const int* __restrict__ dst = (type ? ei_s + Es : ei_n + En);
    const int vbase = type ? N : 0;
    int per = ((E + SLICES - 1) / SLICES + 3) & ~3;
    const int e0 = blockIdx.x * per;
    const int e1 = min(e0 + per, E);
    int i = e0 + (int)threadIdx.x * 4;
    for (; i + 3 < e1; i += 256 * 4) {
        int4 d4 = *(const int4*)(dst + i);
        atomicAdd(&bh[(vbase + d4.x) >> BSHIFT], 1);
        atomicAdd(&bh[(vbase + d4.y) >> BSHIFT], 1);
        atomicAdd(&bh[(vbase + d4.z) >> BSHIFT], 1);
        atomicAdd(&bh[(vbase + d4.w) >> BSHIFT], 1);
    }
    for (; i < e1; ++i) atomicAdd(&bh[(vbase + dst[i]) >> BSHIFT], 1);
    __syncthreads();
    const int g = type * SLICES + blockIdx.x;
    for (int b = threadIdx.x; b < nb; b += 256) counts[(size_t)g * nb + b] = bh[b];
}

// ---------------- 2. scan over slices, per bucket (IN-PLACE: counts->offsets) ----
__global__ __launch_bounds__(G2)
void scanA_kernel(int* __restrict__ counts, int* __restrict__ totals, int nb) {
    __shared__ int s[G2];
    const int b = blockIdx.x;
    const int g = threadIdx.x;
    int c = counts[(size_t)g * nb + b];
    s[g] = c;
    __syncthreads();
    for (int o = 1; o < G2; o <<= 1) {
        int t = (g >= o) ? s[g - o] : 0;
        __syncthreads();
        s[g] += t;
        __syncthreads();
    }
    counts[(size_t)g * nb + b] = s[g] - c;   // exclusive within bucket
    if (g == G2 - 1) totals[b] = s[g];
}

// ---------------- 3. scan over buckets (bases padded to mult of 4) ----------------
__global__ __launch_bounds__(1024)
void scanB_kernel(const int* __restrict__ totals, int* __restrict__ bucket_base, int nb) {
    __shared__ int s[1024];
    const int g = threadIdx.x;
    int c = (g < nb) ? ((totals[g] + 3) & ~3) : 0;   // pad: keeps uint4 loads aligned
    s[g] = c;
    __syncthreads();
    for (int o = 1; o < 1024; o <<= 1) {
        int t = (g >= o) ? s[g - o] : 0;
        __syncthreads();
        s[g] += t;
        __syncthreads();
    }
    if (g < nb) bucket_base[g] = s[g] - c;
}

// ---------------- 4. placement: scatter codes into bucket segments ----------------
__global__ __launch_bounds__(256)
void place_kernel(const int* __restrict__ ei_n, const int* __restrict__ ei_s,
                  const int* __restrict__ offsets, const int* __restrict__ bucket_base,
                  unsigned int* __restrict__ codes, int N, int En, int Es, int nb) {
    __shared__ int cur[NB_MAX];
    const int type = blockIdx.y;
    const int g = type * SLICES + blockIdx.x;
    for (int b = threadIdx.x; b < nb; b += 256)
        cur[b] = offsets[(size_t)g * nb + b] + bucket_base[b];
    __syncthreads();
    const int* __restrict__ ei = type ? ei_s : ei_n;
    const int E = type ? Es : En;
    const int vbase = type ? N : 0;
    int per = ((E + SLICES - 1) / SLICES + 3) & ~3;
    const int e0 = blockIdx.x * per;
    const int e1 = min(e0 + per, E);

#define PLACE(sv, dv) do {                                             \
        int vd = vbase + (dv); int bb = vd >> BSHIFT;                  \
        int pos = atomicAdd(&cur[bb], 1);                              \
        codes[pos] = ((unsigned)(vd & (BSZ - 1)) << 18)                \
                   | (unsigned)(vbase + (sv));                         \
    } while (0)

    int i = e0 + (int)threadIdx.x * 4;
    for (; i + 3 < e1; i += 256 * 4) {
        int4 s4 = *(const int4*)(ei + i);
        int4 d4 = *(const int4*)(ei + E + i);
        PLACE(s4.x, d4.x);
        PLACE(s4.y, d4.y);
        PLACE(s4.z, d4.z);
        PLACE(s4.w, d4.w);
    }
    for (; i < e1; ++i) PLACE(ei[i], ei[E + i]);
#undef PLACE
}

// ---------------- 5. per-dst degree from sorted codes ----------------
__global__ __launch_bounds__(256)
void dcount_kernel(const unsigned int* __restrict__ codes, const int* __restrict__ bucket_base,
                   const int* __restrict__ totals, int* __restrict__ cnt, int M) {
    __shared__ int dcnt[BSZ];
    dcnt[threadIdx.x] = 0;
    __syncthreads();
    const int b = blockIdx.x;
    const int base = bucket_base[b];
    const int end = base + totals[b];
    for (int e = base + (int)threadIdx.x; e < end; e += 256)
        atomicAdd(&dcnt[codes[e] >> 18], 1);
    __syncthreads();
    const int vnode = b * BSZ + (int)threadIdx.x;
    if (vnode < M) cnt[vnode] = dcnt[threadIdx.x];
}

// ---------------- 6. xws[type][node] = (x @ W) * rsqrt(deg+1), __half2 ----------------
__global__ void xw_kernel(const float* __restrict__ x,
                          const float* __restrict__ Wn, const float* __restrict__ Ws,
                          const int* __restrict__ cnt,
                          __half2* __restrict__ xws, int N) {
    __shared__ float wn[64 * 32];
    __shared__ float wsm[64 * 32];
    for (int i = threadIdx.x; i < 64 * 32; i += blockDim.x) {
        wn[i] = Wn[i];
        wsm[i] = Ws[i];
    }
    __syncthreads();
    int lane = threadIdx.x & 31;
    int node = blockIdx.x * (blockDim.x >> 5) + (threadIdx.x >> 5);
    if (node >= N) return;

    const float4* x4 = (const float4*)(x + (size_t)node * 64);
    float an = 0.f, as = 0.f;
#pragma unroll
    for (int k4 = 0; k4 < 16; ++k4) {
        float4 xv = x4[k4];
        int k = k4 * 4;
        an += xv.x * wn[(k + 0) * 32 + lane] + xv.y * wn[(k + 1) * 32 + lane]
            + xv.z * wn[(k + 2) * 32 + lane] + xv.w * wn[(k + 3) * 32 + lane];
        as += xv.x * wsm[(k + 0) * 32 + lane] + xv.y * wsm[(k + 1) * 32 + lane]
            + xv.z * wsm[(k + 2) * 32 + lane] + xv.w * wsm[(k + 3) * 32 + lane];
    }
    float vn = an * rsqrtf((float)cnt[node] + 1.0f);
    float vs = as * rsqrtf((float)cnt[N + node] + 1.0f);
    int sl = lane & 15;
    float vn0 = __shfl(vn, 2 * sl, 32);
    float vn1 = __shfl(vn, 2 * sl + 1, 32);
    float vs0 = __shfl(vs, 2 * sl, 32);
    float vs1 = __shfl(vs, 2 * sl + 1, 32);
    if (lane < 16) {
        xws[(size_t)node * 16 + sl] = __floats2half2_rn(vn0, vn1);
        xws[((size_t)N + node) * 16 + sl] = __floats2half2_rn(vs0, vs1);
    }
}

// ---------------- 7. per-bucket fixed-point LDS accumulate + dense flush ----------
__global__ __launch_bounds__(512)
void gather_kernel(const unsigned int* __restrict__ codes, const int* __restrict__ bucket_base,
                   const int* __restrict__ totals, const __half2* __restrict__ xws,
                   __half2* __restrict__ acc, int M) {
    __shared__ int facc[BSZ * LDSPAD];   // 33.8 KB -> up to 4 blocks/CU
    for (int i = threadIdx.x; i < BSZ * LDSPAD; i += 512) facc[i] = 0;
    __syncthreads();
    const int b = blockIdx.x;
    const int base = bucket_base[b];            // multiple of 4 (scanB pad)
    const int end = base + totals[b];
    const int sl = threadIdx.x & 15;
    const int grp = threadIdx.x >> 4;           // 32 groups of 16 lanes

    // native ds_add_u32 fixed-point accumulate (NO float CAS loops)
#define ACC_EDGE(cc, ww) do {                                                \
        float2 f_ = __half22float2(ww);                                      \
        int r_ = (int)((cc) >> 18) * LDSPAD + 2 * sl;                        \
        atomicAdd(&facc[r_],     __float2int_rn(f_.x * FXS));                \
        atomicAdd(&facc[r_ + 1], __float2int_rn(f_.y * FXS));                \
    } while (0)

    for (int e = base + grp * 8; e + 7 < end; e += 32 * 8) {
        uint4 ca = *(const uint4*)(codes + e);
        uint4 cb = *(const uint4*)(codes + e + 4);
        // issue all 8 gathers before any LDS op
        __half2 w0 = xws[(size_t)(ca.x & 0x3FFFFu) * 16 + sl];
        __half2 w1 = xws[(size_t)(ca.y & 0x3FFFFu) * 16 + sl];
        __half2 w2 = xws[(size_t)(ca.z & 0x3FFFFu) * 16 + sl];
        __half2 w3 = xws[(size_t)(ca.w & 0x3FFFFu) * 16 + sl];
        __half2 w4 = xws[(size_t)(cb.x & 0x3FFFFu) * 16 + sl];
        __half2 w5 = xws[(size_t)(cb.y & 0x3FFFFu) * 16 + sl];
        __half2 w6 = xws[(size_t)(cb.z & 0x3FFFFu) * 16 + sl];
        __half2 w7 = xws[(size_t)(cb.w & 0x3FFFFu) * 16 + sl];
        ACC_EDGE(ca.x, w0);
        ACC_EDGE(ca.y, w1);
        ACC_EDGE(ca.z, w2);
        ACC_EDGE(ca.w, w3);
        ACC_EDGE(cb.x, w4);
        ACC_EDGE(cb.y, w5);
        ACC_EDGE(cb.z, w6);
        ACC_EDGE(cb.w, w7);
    }
    const int t0 = base + ((end - base) & ~7);
    if (grp < end - t0) {
        unsigned c = codes[t0 + grp];
        __half2 w = xws[(size_t)(c & 0x3FFFFu) * 16 + sl];
        ACC_EDGE(c, w);
    }
#undef ACC_EDGE

    __syncthreads();
    for (int i = threadIdx.x; i < BSZ * 16; i += 512) {
        int dl = i >> 4, s = i & 15;
        int vnode = b * BSZ + dl;
        if (vnode < M) {
            float f0 = (float)facc[dl * LDSPAD + 2 * s] * FXSI;
            float f1 = (float)facc[dl * LDSPAD + 2 * s + 1] * FXSI;
            acc[(size_t)vnode * 16 + s] = __floats2half2_rn(f0, f1);
        }
    }
}

// ---------------- 8. epilogue (adds self-loop term from xws) ----------------
__global__ void epilogue_kernel(const __half2* __restrict__ acc, const __half2* __restrict__ xws,
                                const int* __restrict__ cnt,
                                const float* __restrict__ b_n, const float* __restrict__ b_s,
                                const float* __restrict__ W_lin, const float* __restrict__ b_lin,
                                float* __restrict__ out, int N) {
    int gid = blockIdx.x * blockDim.x + threadIdx.x;
    int node = gid >> 4, sl = gid & 15;
    if (node >= N) return;
    float2 an = __half22float2(acc[(size_t)node * 16 + sl]);
    float2 ns = __half22float2(xws[(size_t)node * 16 + sl]);
    float2 as = __half22float2(acc[((size_t)N + node) * 16 + sl]);
    float2 ss = __half22float2(xws[((size_t)N + node) * 16 + sl]);
    float dn = rsqrtf((float)cnt[node] + 1.0f);
    float dsv = rsqrtf((float)cnt[N + node] + 1.0f);
    float h0 = (an.x + ns.x) * dn + b_n[2 * sl] + (as.x + ss.x) * dsv + b_s[2 * sl];
    float h1 = (an.y + ns.y) * dn + b_n[2 * sl + 1] + (as.y + ss.y) * dsv + b_s[2 * sl + 1];
    float p = fmaxf(h0, 0.f) * W_lin[2 * sl] + fmaxf(h1, 0.f) * W_lin[2 * sl + 1];
#pragma unroll
    for (int off = 8; off > 0; off >>= 1) p += __shfl_xor(p, off, 16);
    if (sl == 0) out[node] = p + b_lin[0];
}

extern "C" void kernel_launch(void* const* d_in, const int* in_sizes, int n_in,
                              void* d_out, int out_size, void* d_ws, size_t ws_size,
                              hipStream_t stream) {
    const float* x     = (const float*)d_in[0];
    const int*   ei_n  = (const int*)d_in[1];
    const int*   ei_s  = (const int*)d_in[2];
    const float* W_n   = (const float*)d_in[3];
    const float* b_n   = (const float*)d_in[4];
    const float* W_s   = (const float*)d_in[5];
    const float* b_s   = (const float*)d_in[6];
    const float* W_lin = (const float*)d_in[7];
    const float* b_lin = (const float*)d_in[8];
    float* out = (float*)d_out;

    const int N  = in_sizes[0] / 64;   // 100000
    const int En = in_sizes[1] / 2;    // 3200000
    const int Es = in_sizes[2] / 2;    // 3200000
    const int M  = 2 * N;              // 200000 vnodes
    const int nb = (M + BSZ - 1) / BSZ;            // 782 buckets
    const size_t Etot = (size_t)En + (size_t)Es;   // 6.4M

    // Workspace layout (~53.7 MB):
    // cnt[M] | counts/offsets[G2*nb] (scanA in-place) | totals[nb]
    // | bucket_base[nb] | codes[Etot + 4*nb] (16B aligned) | xws | acc
    int* cnt         = (int*)d_ws;
    int* counts      = cnt + M;
    int* totals      = counts + (size_t)G2 * nb;
    int* bucket_base = totals + nb;
    uintptr_t pcodes = (uintptr_t)(bucket_base + nb);
    pcodes = (pcodes + 15) & ~(uintptr_t)15;
    unsigned int* codes = (unsigned int*)pcodes;
    __half2* xws = (__half2*)(codes + Etot + 4 * (size_t)nb);
    __half2* acc = xws + (size_t)16 * M;

    bhist_kernel<<<dim3(SLICES, 2), 256, 0, stream>>>(ei_n, ei_s, counts, N, En, Es, nb);
    scanA_kernel<<<nb, G2, 0, stream>>>(counts, totals, nb);
    scanB_kernel<<<1, 1024, 0, stream>>>(totals, bucket_base, nb);
    place_kernel<<<dim3(SLICES, 2), 256, 0, stream>>>(ei_n, ei_s, counts, bucket_base,
                                                      codes, N, En, Es, nb);
    dcount_kernel<<<nb, 256, 0, stream>>>(codes, bucket_base, totals, cnt, M);
    xw_kernel<<<(N + 7) / 8, 256, 0, stream>>>(x, W_n, W_s, cnt, xws, N);
    gather_kernel<<<nb, 512, 0, stream>>>(codes, bucket_base, totals, xws, acc, M);
    epilogue_kernel<<<(int)(((size_t)N * 16 + 255) / 256), 256, 0, stream>>>(
        acc, xws, cnt, b_n, b_s, W_lin, b_lin, out, N);
}

// Round 3
// 378.483 us; speedup vs baseline: 4.1556x; 1.0033x over previous
//
#include <hip/hip_runtime.h>
#include <hip/hip_fp16.h>

// R14: R13 counting-sort pipeline +
//  (a) vnode renumber vn = 2*node + type  -> both types of a node share a
//      bucket (bucket = d>>7), so gather's flush computes the FINAL output
//      in-place (epilogue kernel + acc array deleted).
//  (b) xw rewritten: 1 node/thread, W^T staged in LDS, wave-uniform
//      ds_read_b128 broadcasts (1 LDS instr / 4 FMA) instead of 128
//      per-lane ds_read_b32 per node (old xw was LDS-issue-bound).
//  (c) gather MLP deepened 8->16 edges per 16-lane group; facc layout
//      feat-x @ row*33+sl, feat-y @ row*33+16+sl (16-consecutive-bank
//      windows -> ~2-way conflicts instead of parity-locked 4-way).
//
// code = (dst_local << 18) | vsrc, dst_local = 2*(d&127)+type (8b), vsrc = 2*s+type (18b)

#define SLICES 256
#define G2     (2 * SLICES)   // 512 slice rows (256 per edge type)
#define BSZ    256            // vnodes per bucket (=128 node pairs)
#define NB_MAX 800
#define LDSPAD 33
#define FXS    65536.0f       // fixed-point scale 2^16
#define FXSI   (1.0f / 65536.0f)

// ---------------- 1. bucket histogram per (slice, type); bucket = d>>7 ----------
__global__ __launch_bounds__(256)
void bhist_kernel(const int* __restrict__ ei_n, const int* __restrict__ ei_s,
                  int* __restrict__ counts, int N, int En, int Es, int nb) {
    __shared__ int bh[NB_MAX];
    for (int b = threadIdx.x; b < nb; b += 256) bh[b] = 0;
    __syncthreads();
    const int type = blockIdx.y;
    const int E = type ? Es : En;
    const int* __restrict__ dst = (type ? ei_s + Es : ei_n + En);
    int per = ((E + SLICES - 1) / SLICES + 3) & ~3;
    const int e0 = blockIdx.x * per;
    const int e1 = min(e0 + per, E);
    int i = e0 + (int)threadIdx.x * 4;
    for (; i + 3 < e1; i += 256 * 4) {
        int4 d4 = *(const int4*)(dst + i);
        atomicAdd(&bh[d4.x >> 7], 1);
        atomicAdd(&bh[d4.y >> 7], 1);
        atomicAdd(&bh[d4.z >> 7], 1);
        atomicAdd(&bh[d4.w >> 7], 1);
    }
    for (; i < e1; ++i) atomicAdd(&bh[dst[i] >> 7], 1);
    __syncthreads();
    const int g = type * SLICES + blockIdx.x;
    for (int b = threadIdx.x; b < nb; b += 256) counts[(size_t)g * nb + b] = bh[b];
}

// ---------------- 2. scan over slices, per bucket (in-place counts->offsets) -----
__global__ __launch_bounds__(G2)
void scanA_kernel(int* __restrict__ counts, int* __restrict__ totals, int nb) {
    __shared__ int s[G2];
    const int b = blockIdx.x;
    const int g = threadIdx.x;
    int c = counts[(size_t)g * nb + b];
    s[g] = c;
    __syncthreads();
    for (int o = 1; o < G2; o <<= 1) {
        int t = (g >= o) ? s[g - o] : 0;
        __syncthreads();
        s[g] += t;
        __syncthreads();
    }
    counts[(size_t)g * nb + b] = s[g] - c;
    if (g == G2 - 1) totals[b] = s[g];
}

// ---------------- 3. scan over buckets (bases padded to mult of 4) ---------------
__global__ __launch_bounds__(1024)
void scanB_kernel(const int* __restrict__ totals, int* __restrict__ bucket_base, int nb) {
    __shared__ int s[1024];
    const int g = threadIdx.x;
    int c = (g < nb) ? ((totals[g] + 3) & ~3) : 0;
    s[g] = c;
    __syncthreads();
    for (int o = 1; o < 1024; o <<= 1) {
        int t = (g >= o) ? s[g - o] : 0;
        __syncthreads();
        s[g] += t;
        __syncthreads();
    }
    if (g < nb) bucket_base[g] = s[g] - c;
}

// ---------------- 4. placement: scatter edge codes into bucket segments ----------
__global__ __launch_bounds__(256)
void place_kernel(const int* __restrict__ ei_n, const int* __restrict__ ei_s,
                  const int* __restrict__ offsets, const int* __restrict__ bucket_base,
                  unsigned int* __restrict__ codes, int N, int En, int Es, int nb) {
    __shared__ int cur[NB_MAX];
    const int type = blockIdx.y;
    const int g = type * SLICES + blockIdx.x;
    for (int b = threadIdx.x; b < nb; b += 256)
        cur[b] = offsets[(size_t)g * nb + b] + bucket_base[b];
    __syncthreads();
    const int* __restrict__ ei = type ? ei_s : ei_n;
    const int E = type ? Es : En;
    int per = ((E + SLICES - 1) / SLICES + 3) & ~3;
    const int e0 = blockIdx.x * per;
    const int e1 = min(e0 + per, E);

#define PLACE(sv, dv) do {                                                \
        int d_ = (dv); int bb = d_ >> 7;                                  \
        int pos = atomicAdd(&cur[bb], 1);                                 \
        codes[pos] = ((unsigned)(2 * (d_ & 127) + type) << 18)            \
                   | (unsigned)(2 * (sv) + type);                         \
    } while (0)

    int i = e0 + (int)threadIdx.x * 4;
    for (; i + 3 < e1; i += 256 * 4) {
        int4 s4 = *(const int4*)(ei + i);
        int4 d4 = *(const int4*)(ei + E + i);
        PLACE(s4.x, d4.x);
        PLACE(s4.y, d4.y);
        PLACE(s4.z, d4.z);
        PLACE(s4.w, d4.w);
    }
    for (; i < e1; ++i) PLACE(ei[i], ei[E + i]);
#undef PLACE
}

// ---------------- 5. per-vnode degree from sorted codes ----------------
__global__ __launch_bounds__(256)
void dcount_kernel(const unsigned int* __restrict__ codes, const int* __restrict__ bucket_base,
                   const int* __restrict__ totals, int* __restrict__ cnt, int M) {
    __shared__ int dcnt[BSZ];
    dcnt[threadIdx.x] = 0;
    __syncthreads();
    const int b = blockIdx.x;
    const int base = bucket_base[b];
    const int end = base + totals[b];
    const int t0 = base + ((end - base) & ~3);
    for (int e = base + (int)threadIdx.x * 4; e < t0; e += 256 * 4) {
        uint4 c = *(const uint4*)(codes + e);
        atomicAdd(&dcnt[c.x >> 18], 1);
        atomicAdd(&dcnt[c.y >> 18], 1);
        atomicAdd(&dcnt[c.z >> 18], 1);
        atomicAdd(&dcnt[c.w >> 18], 1);
    }
    if ((int)threadIdx.x < end - t0) atomicAdd(&dcnt[codes[t0 + threadIdx.x] >> 18], 1);
    __syncthreads();
    const int vnode = b * BSZ + (int)threadIdx.x;
    if (vnode < M) cnt[vnode] = dcnt[threadIdx.x];
}

// ---------------- 6. xw: 1 node/thread, W^T LDS broadcast reads ----------------
// xws[(2*node+type)*16 + sl] = half2(feat 2sl, 2sl+1) of (x@W)*rsqrt(deg+1)
__global__ __launch_bounds__(256)
void xw_kernel(const float* __restrict__ x,
               const float* __restrict__ Wn, const float* __restrict__ Ws,
               const int* __restrict__ cnt,
               __half2* __restrict__ xws, int N) {
    __shared__ float wtn[32 * 64];   // W^T: [h][k]
    __shared__ float wts[32 * 64];
    for (int i = threadIdx.x; i < 64 * 32; i += 256) {
        int k = i >> 5, h = i & 31;
        wtn[h * 64 + k] = Wn[i];
        wts[h * 64 + k] = Ws[i];
    }
    __syncthreads();
    int node = blockIdx.x * 256 + threadIdx.x;
    if (node >= N) return;

    float xr[64];
    const float4* x4 = (const float4*)(x + (size_t)node * 64);
#pragma unroll
    for (int q = 0; q < 16; ++q) {
        float4 v = x4[q];
        xr[4 * q] = v.x; xr[4 * q + 1] = v.y; xr[4 * q + 2] = v.z; xr[4 * q + 3] = v.w;
    }
    float dn = rsqrtf((float)cnt[2 * node] + 1.0f);
    float ds = rsqrtf((float)cnt[2 * node + 1] + 1.0f);

    unsigned pn[16], ps[16];
#pragma unroll
    for (int s2 = 0; s2 < 16; ++s2) {
        float a0n = 0.f, a1n = 0.f, a0s = 0.f, a1s = 0.f;
#pragma unroll
        for (int q = 0; q < 16; ++q) {
            // wave-uniform addresses -> LDS broadcast, no conflicts
            float4 w0n = *(const float4*)&wtn[(2 * s2) * 64 + 4 * q];
            float4 w1n = *(const float4*)&wtn[(2 * s2 + 1) * 64 + 4 * q];
            float4 w0s = *(const float4*)&wts[(2 * s2) * 64 + 4 * q];
            float4 w1s = *(const float4*)&wts[(2 * s2 + 1) * 64 + 4 * q];
            float x0 = xr[4 * q], x1 = xr[4 * q + 1], x2 = xr[4 * q + 2], x3 = xr[4 * q + 3];
            a0n += x0 * w0n.x + x1 * w0n.y + x2 * w0n.z + x3 * w0n.w;
            a1n += x0 * w1n.x + x1 * w1n.y + x2 * w1n.z + x3 * w1n.w;
            a0s += x0 * w0s.x + x1 * w0s.y + x2 * w0s.z + x3 * w0s.w;
            a1s += x0 * w1s.x + x1 * w1s.y + x2 * w1s.z + x3 * w1s.w;
        }
        __half2 hn = __floats2half2_rn(a0n * dn, a1n * dn);
        __half2 hs = __floats2half2_rn(a0s * ds, a1s * ds);
        pn[s2] = *(unsigned*)&hn;
        ps[s2] = *(unsigned*)&hs;
    }
    uint4* on = (uint4*)(xws + (size_t)(2 * node) * 16);
    uint4* os = (uint4*)(xws + (size_t)(2 * node + 1) * 16);
#pragma unroll
    for (int q = 0; q < 4; ++q) {
        on[q] = make_uint4(pn[4 * q], pn[4 * q + 1], pn[4 * q + 2], pn[4 * q + 3]);
        os[q] = make_uint4(ps[4 * q], ps[4 * q + 1], ps[4 * q + 2], ps[4 * q + 3]);
    }
}

// ---------------- 7. gather: fixed-point LDS accumulate + FUSED epilogue --------
__global__ __launch_bounds__(512)
void gather_kernel(const unsigned int* __restrict__ codes, const int* __restrict__ bucket_base,
                   const int* __restrict__ totals, const __half2* __restrict__ xws,
                   const int* __restrict__ cnt,
                   const float* __restrict__ b_n, const float* __restrict__ b_s,
                   const float* __restrict__ W_lin, const float* __restrict__ b_lin,
                   float* __restrict__ out, int N) {
    __shared__ int facc[BSZ * LDSPAD];   // 33.8 KB
    for (int i = threadIdx.x; i < BSZ * LDSPAD; i += 512) facc[i] = 0;
    __syncthreads();
    const int b = blockIdx.x;
    const int base = bucket_base[b];            // multiple of 4
    const int end = base + totals[b];
    const int sl = threadIdx.x & 15;
    const int grp = threadIdx.x >> 4;           // 32 groups of 16 lanes

#define GA(cc) xws[(size_t)((cc) & 0x3FFFFu) * 16 + sl]
#define ACC_EDGE(cc, ww) do {                                                \
        float2 f_ = __half22float2(ww);                                      \
        int r_ = (int)((cc) >> 18) * LDSPAD + sl;                            \
        atomicAdd(&facc[r_],      __float2int_rn(f_.x * FXS));               \
        atomicAdd(&facc[r_ + 16], __float2int_rn(f_.y * FXS));               \
    } while (0)

    const int t0 = base + ((end - base) & ~15);
    for (int e = base + grp * 16; e < t0; e += 32 * 16) {
        uint4 c0 = *(const uint4*)(codes + e);
        uint4 c1 = *(const uint4*)(codes + e + 4);
        uint4 c2 = *(const uint4*)(codes + e + 8);
        uint4 c3 = *(const uint4*)(codes + e + 12);
        // all 16 gathers issue before any LDS op
        __half2 w0 = GA(c0.x), w1 = GA(c0.y), w2 = GA(c0.z), w3 = GA(c0.w);
        __half2 w4 = GA(c1.x), w5 = GA(c1.y), w6 = GA(c1.z), w7 = GA(c1.w);
        __half2 w8 = GA(c2.x), w9 = GA(c2.y), wA = GA(c2.z), wB = GA(c2.w);
        __half2 wC = GA(c3.x), wD = GA(c3.y), wE = GA(c3.z), wF = GA(c3.w);
        ACC_EDGE(c0.x, w0); ACC_EDGE(c0.y, w1); ACC_EDGE(c0.z, w2); ACC_EDGE(c0.w, w3);
        ACC_EDGE(c1.x, w4); ACC_EDGE(c1.y, w5); ACC_EDGE(c1.z, w6); ACC_EDGE(c1.w, w7);
        ACC_EDGE(c2.x, w8); ACC_EDGE(c2.y, w9); ACC_EDGE(c2.z, wA); ACC_EDGE(c2.w, wB);
        ACC_EDGE(c3.x, wC); ACC_EDGE(c3.y, wD); ACC_EDGE(c3.z, wE); ACC_EDGE(c3.w, wF);
    }
    for (int e = t0 + grp; e < end; e += 32) {
        unsigned c = codes[e];
        __half2 w = GA(c);
        ACC_EDGE(c, w);
    }
#undef ACC_EDGE
#undef GA

    __syncthreads();
    // fused epilogue: bucket holds 128 node pairs (vnode 2n, 2n+1)
    const float bn0 = b_n[2 * sl], bn1 = b_n[2 * sl + 1];
    const float bs0 = b_s[2 * sl], bs1 = b_s[2 * sl + 1];
    const float wl0 = W_lin[2 * sl], wl1 = W_lin[2 * sl + 1];
    const float bl  = b_lin[0];
    for (int p = grp; p < 128; p += 32) {
        int node = b * 128 + p;
        if (node >= N) break;
        int rn = (2 * p) * LDSPAD, rs = rn + LDSPAD;
        float anx = (float)facc[rn + sl] * FXSI, any_ = (float)facc[rn + 16 + sl] * FXSI;
        float asx = (float)facc[rs + sl] * FXSI, asy  = (float)facc[rs + 16 + sl] * FXSI;
        float2 ns = __half22float2(xws[(size_t)(2 * node) * 16 + sl]);
        float2 ss = __half22float2(xws[(size_t)(2 * node + 1) * 16 + sl]);
        float dn  = rsqrtf((float)cnt[2 * node] + 1.0f);
        float dsv = rsqrtf((float)cnt[2 * node + 1] + 1.0f);
        float h0 = (anx + ns.x) * dn + bn0 + (asx + ss.x) * dsv + bs0;
        float h1 = (any_ + ns.y) * dn + bn1 + (asy + ss.y) * dsv + bs1;
        float pr = fmaxf(h0, 0.f) * wl0 + fmaxf(h1, 0.f) * wl1;
#pragma unroll
        for (int off = 8; off > 0; off >>= 1) pr += __shfl_xor(pr, off, 16);
        if (sl == 0) out[node] = pr + bl;
    }
}

extern "C" void kernel_launch(void* const* d_in, const int* in_sizes, int n_in,
                              void* d_out, int out_size, void* d_ws, size_t ws_size,
                              hipStream_t stream) {
    const float* x     = (const float*)d_in[0];
    const int*   ei_n  = (const int*)d_in[1];
    const int*   ei_s  = (const int*)d_in[2];
    const float* W_n   = (const float*)d_in[3];
    const float* b_n   = (const float*)d_in[4];
    const float* W_s   = (const float*)d_in[5];
    const float* b_s   = (const float*)d_in[6];
    const float* W_lin = (const float*)d_in[7];
    const float* b_lin = (const float*)d_in[8];
    float* out = (float*)d_out;

    const int N  = in_sizes[0] / 64;   // 100000
    const int En = in_sizes[1] / 2;    // 3200000
    const int Es = in_sizes[2] / 2;    // 3200000
    const int M  = 2 * N;              // 200000 vnodes (vn = 2*node + type)
    const int nb = (M + BSZ - 1) / BSZ;            // 782 buckets
    const size_t Etot = (size_t)En + (size_t)Es;   // 6.4M

    // Workspace (~41 MB): cnt[M] | counts/offsets[G2*nb] | totals[nb]
    // | bucket_base[nb] | codes[Etot + 4*nb] (16B aligned) | xws[16*M half2]
    int* cnt         = (int*)d_ws;
    int* counts      = cnt + M;
    int* totals      = counts + (size_t)G2 * nb;
    int* bucket_base = totals + nb;
    uintptr_t pcodes = (uintptr_t)(bucket_base + nb);
    pcodes = (pcodes + 15) & ~(uintptr_t)15;
    unsigned int* codes = (unsigned int*)pcodes;
    __half2* xws = (__half2*)(codes + Etot + 4 * (size_t)nb);

    bhist_kernel<<<dim3(SLICES, 2), 256, 0, stream>>>(ei_n, ei_s, counts, N, En, Es, nb);
    scanA_kernel<<<nb, G2, 0, stream>>>(counts, totals, nb);
    scanB_kernel<<<1, 1024, 0, stream>>>(totals, bucket_base, nb);
    place_kernel<<<dim3(SLICES, 2), 256, 0, stream>>>(ei_n, ei_s, counts, bucket_base,
                                                      codes, N, En, Es, nb);
    dcount_kernel<<<nb, 256, 0, stream>>>(codes, bucket_base, totals, cnt, M);
    xw_kernel<<<(N + 255) / 256, 256, 0, stream>>>(x, W_n, W_s, cnt, xws, N);
    gather_kernel<<<nb, 512, 0, stream>>>(codes, bucket_base, totals, xws, cnt,
                                          b_n, b_s, W_lin, b_lin, out, N);
}

// Round 4
// 371.480 us; speedup vs baseline: 4.2340x; 1.0189x over previous
//
#include <hip/hip_runtime.h>
#include <hip/hip_fp16.h>

// R15: kill the hidden cost in place (theory: 6.4M per-lane scattered 4B
// stores = ~6.4M line touches at ~46 G/s ~= 135us, hiding just under
// gather's 139us in the top-5 cutoff).
//  - place is now an LDS radix-partition: per 4096-edge chunk: LDS hist
//    (rank from ds_add return) -> block scan -> dense LDS scatter ->
//    per-bucket global cursor reservation (one atomicAdd per bucket) ->
//    contiguous run flush. Line touches 6.4M -> ~1M.
//  - positions come from atomic cursors => scanA deleted; bhist flushes to
//    global btot via int atomics; 1-block scan makes bucket_base + gcur.
//  - gather/dcount use end = gcur[b] (post-place cursor); totals deleted.
// gather itself unchanged (at the ~46 G line/s random-gather floor).
//
// code = (dst_local << 18) | vsrc; dst_local = 2*(d&127)+type; vsrc = 2*s+type

#define SLICES 256
#define BSZ    256            // vnodes per bucket (=128 node pairs)
#define NB_MAX 800
#define LDSPAD 33
#define PCH    4096           // place: edges per chunk (512 thr x 8)
#define FXS    65536.0f
#define FXSI   (1.0f / 65536.0f)

// ---------------- 1. bucket histogram -> global btot (int atomics) -------------
__global__ __launch_bounds__(256)
void bhist_kernel(const int* __restrict__ ei_n, const int* __restrict__ ei_s,
                  int* __restrict__ btot, int N, int En, int Es, int nb) {
    __shared__ int bh[NB_MAX];
    for (int b = threadIdx.x; b < nb; b += 256) bh[b] = 0;
    __syncthreads();
    const int type = blockIdx.y;
    const int E = type ? Es : En;
    const int* __restrict__ dst = (type ? ei_s + Es : ei_n + En);
    int per = ((E + SLICES - 1) / SLICES + 3) & ~3;
    const int e0 = blockIdx.x * per;
    const int e1 = min(e0 + per, E);
    int i = e0 + (int)threadIdx.x * 4;
    for (; i + 3 < e1; i += 256 * 4) {
        int4 d4 = *(const int4*)(dst + i);
        atomicAdd(&bh[d4.x >> 7], 1);
        atomicAdd(&bh[d4.y >> 7], 1);
        atomicAdd(&bh[d4.z >> 7], 1);
        atomicAdd(&bh[d4.w >> 7], 1);
    }
    for (; i < e1; ++i) atomicAdd(&bh[dst[i] >> 7], 1);
    __syncthreads();
    for (int b = threadIdx.x; b < nb; b += 256) {
        int v = bh[b];
        if (v) atomicAdd(&btot[b], v);
    }
}

// ---------------- 2. scan buckets: base (4-padded) + init cursors --------------
__global__ __launch_bounds__(1024)
void scan_kernel(const int* __restrict__ btot, int* __restrict__ bucket_base,
                 int* __restrict__ gcur, int nb) {
    __shared__ int s[1024];
    const int g = threadIdx.x;
    int c = (g < nb) ? ((btot[g] + 3) & ~3) : 0;   // pad: keep uint4 alignment
    s[g] = c;
    __syncthreads();
    for (int o = 1; o < 1024; o <<= 1) {
        int t = (g >= o) ? s[g - o] : 0;
        __syncthreads();
        s[g] += t;
        __syncthreads();
    }
    if (g < nb) {
        int b = s[g] - c;
        bucket_base[g] = b;
        gcur[g] = b;
    }
}

// ---------------- 3. place: LDS radix-partition, line-dense flush --------------
__global__ __launch_bounds__(512)
void place_kernel(const int* __restrict__ ei_n, const int* __restrict__ ei_s,
                  int* __restrict__ gcur, unsigned int* __restrict__ codes,
                  int N, int En, int Es, int nb) {
    __shared__ unsigned stage[PCH];      // 16 KB
    __shared__ int hist[NB_MAX];         // 3.2 KB
    __shared__ int base[NB_MAX];         // 3.2 KB
    __shared__ int gb[NB_MAX];           // 3.2 KB
    __shared__ int h2[NB_MAX / 2];       // 1.6 KB
    const int t = threadIdx.x;
    const int type = blockIdx.y;
    const int* __restrict__ ei = type ? ei_s : ei_n;
    const int E = type ? Es : En;
    int per = ((E + SLICES - 1) / SLICES + 7) & ~7;
    const int e0 = blockIdx.x * per;
    const int e1 = min(e0 + per, E);
    const int P = (nb + 1) >> 1;

    for (int c0 = e0; c0 < e1; c0 += PCH) {
        for (int b = t; b < nb; b += 512) hist[b] = 0;
        __syncthreads();

        const int i = c0 + t * 8;
        int nv = e1 - i;
        nv = nv < 0 ? 0 : (nv > 8 ? 8 : nv);
        unsigned cd[8];
        int bb[8], rk[8];
        if (nv == 8) {
            int4 sA = *(const int4*)(ei + i),     sB = *(const int4*)(ei + i + 4);
            int4 dA = *(const int4*)(ei + E + i), dB = *(const int4*)(ei + E + i + 4);
            int ss[8] = {sA.x, sA.y, sA.z, sA.w, sB.x, sB.y, sB.z, sB.w};
            int dd[8] = {dA.x, dA.y, dA.z, dA.w, dB.x, dB.y, dB.z, dB.w};
#pragma unroll
            for (int j = 0; j < 8; ++j) {
                bb[j] = dd[j] >> 7;
                cd[j] = ((unsigned)(2 * (dd[j] & 127) + type) << 18)
                      | (unsigned)(2 * ss[j] + type);
            }
        } else {
            for (int j = 0; j < nv; ++j) {
                int sv = ei[i + j], dv = ei[E + i + j];
                bb[j] = dv >> 7;
                cd[j] = ((unsigned)(2 * (dv & 127) + type) << 18)
                      | (unsigned)(2 * sv + type);
            }
        }
#pragma unroll
        for (int j = 0; j < 8; ++j)
            if (j < nv) rk[j] = atomicAdd(&hist[bb[j]], 1);
        __syncthreads();

        // exclusive scan of hist[0..nb) via 2-elem pairing + Hillis on h2[0..P)
        if (t < P) {
            int a = hist[2 * t];
            int b2 = (2 * t + 1 < nb) ? hist[2 * t + 1] : 0;
            h2[t] = a + b2;
        }
        __syncthreads();
        for (int o = 1; o < P; o <<= 1) {
            int v = (t < P && t >= o) ? h2[t - o] : 0;
            __syncthreads();
            if (t < P) h2[t] += v;
            __syncthreads();
        }
        if (t < P) {
            int a = hist[2 * t];
            int b2 = (2 * t + 1 < nb) ? hist[2 * t + 1] : 0;
            int inc = h2[t];
            base[2 * t] = inc - a - b2;
            if (2 * t + 1 < nb) base[2 * t + 1] = inc - b2;
        }
        __syncthreads();

        // reserve global space (one atomic per non-empty bucket per chunk)
        for (int b = t; b < nb; b += 512) {
            int c = hist[b];
            gb[b] = c ? atomicAdd(&gcur[b], c) : 0;
        }
        // dense LDS scatter
#pragma unroll
        for (int j = 0; j < 8; ++j)
            if (j < nv) stage[base[bb[j]] + rk[j]] = cd[j];
        __syncthreads();

        // flush: thread b copies bucket b's run contiguously (line-dense)
        for (int b = t; b < nb; b += 512) {
            int c = hist[b], g0 = gb[b], l0 = base[b];
            for (int k = 0; k < c; ++k) codes[g0 + k] = stage[l0 + k];
        }
        __syncthreads();
    }
}

// ---------------- 4. per-vnode degree from binned codes ----------------
__global__ __launch_bounds__(256)
void dcount_kernel(const unsigned int* __restrict__ codes, const int* __restrict__ bucket_base,
                   const int* __restrict__ gcur, int* __restrict__ cnt, int M) {
    __shared__ int dcnt[BSZ];
    dcnt[threadIdx.x] = 0;
    __syncthreads();
    const int b = blockIdx.x;
    const int base = bucket_base[b];
    const int end = gcur[b];
    const int t0 = base + ((end - base) & ~3);
    for (int e = base + (int)threadIdx.x * 4; e < t0; e += 256 * 4) {
        uint4 c = *(const uint4*)(codes + e);
        atomicAdd(&dcnt[c.x >> 18], 1);
        atomicAdd(&dcnt[c.y >> 18], 1);
        atomicAdd(&dcnt[c.z >> 18], 1);
        atomicAdd(&dcnt[c.w >> 18], 1);
    }
    if ((int)threadIdx.x < end - t0) atomicAdd(&dcnt[codes[t0 + threadIdx.x] >> 18], 1);
    __syncthreads();
    const int vnode = b * BSZ + (int)threadIdx.x;
    if (vnode < M) cnt[vnode] = dcnt[threadIdx.x];
}

// ---------------- 5. xw: 1 node/thread, W^T LDS broadcast reads ----------------
__global__ __launch_bounds__(256)
void xw_kernel(const float* __restrict__ x,
               const float* __restrict__ Wn, const float* __restrict__ Ws,
               const int* __restrict__ cnt,
               __half2* __restrict__ xws, int N) {
    __shared__ float wtn[32 * 64];   // W^T: [h][k]
    __shared__ float wts[32 * 64];
    for (int i = threadIdx.x; i < 64 * 32; i += 256) {
        int k = i >> 5, h = i & 31;
        wtn[h * 64 + k] = Wn[i];
        wts[h * 64 + k] = Ws[i];
    }
    __syncthreads();
    int node = blockIdx.x * 256 + threadIdx.x;
    if (node >= N) return;

    float xr[64];
    const float4* x4 = (const float4*)(x + (size_t)node * 64);
#pragma unroll
    for (int q = 0; q < 16; ++q) {
        float4 v = x4[q];
        xr[4 * q] = v.x; xr[4 * q + 1] = v.y; xr[4 * q + 2] = v.z; xr[4 * q + 3] = v.w;
    }
    float dn = rsqrtf((float)cnt[2 * node] + 1.0f);
    float ds = rsqrtf((float)cnt[2 * node + 1] + 1.0f);

    unsigned pn[16], ps[16];
#pragma unroll
    for (int s2 = 0; s2 < 16; ++s2) {
        float a0n = 0.f, a1n = 0.f, a0s = 0.f, a1s = 0.f;
#pragma unroll
        for (int q = 0; q < 16; ++q) {
            float4 w0n = *(const float4*)&wtn[(2 * s2) * 64 + 4 * q];
            float4 w1n = *(const float4*)&wtn[(2 * s2 + 1) * 64 + 4 * q];
            float4 w0s = *(const float4*)&wts[(2 * s2) * 64 + 4 * q];
            float4 w1s = *(const float4*)&wts[(2 * s2 + 1) * 64 + 4 * q];
            float x0 = xr[4 * q], x1 = xr[4 * q + 1], x2 = xr[4 * q + 2], x3 = xr[4 * q + 3];
            a0n += x0 * w0n.x + x1 * w0n.y + x2 * w0n.z + x3 * w0n.w;
            a1n += x0 * w1n.x + x1 * w1n.y + x2 * w1n.z + x3 * w1n.w;
            a0s += x0 * w0s.x + x1 * w0s.y + x2 * w0s.z + x3 * w0s.w;
            a1s += x0 * w1s.x + x1 * w1s.y + x2 * w1s.z + x3 * w1s.w;
        }
        __half2 hn = __floats2half2_rn(a0n * dn, a1n * dn);
        __half2 hs = __floats2half2_rn(a0s * ds, a1s * ds);
        pn[s2] = *(unsigned*)&hn;
        ps[s2] = *(unsigned*)&hs;
    }
    uint4* on = (uint4*)(xws + (size_t)(2 * node) * 16);
    uint4* os = (uint4*)(xws + (size_t)(2 * node + 1) * 16);
#pragma unroll
    for (int q = 0; q < 4; ++q) {
        on[q] = make_uint4(pn[4 * q], pn[4 * q + 1], pn[4 * q + 2], pn[4 * q + 3]);
        os[q] = make_uint4(ps[4 * q], ps[4 * q + 1], ps[4 * q + 2], ps[4 * q + 3]);
    }
}

// ---------------- 6. gather: fixed-point LDS accumulate + fused epilogue -------
__global__ __launch_bounds__(512)
void gather_kernel(const unsigned int* __restrict__ codes, const int* __restrict__ bucket_base,
                   const int* __restrict__ gcur, const __half2* __restrict__ xws,
                   const int* __restrict__ cnt,
                   const float* __restrict__ b_n, const float* __restrict__ b_s,
                   const float* __restrict__ W_lin, const float* __restrict__ b_lin,
                   float* __restrict__ out, int N) {
    __shared__ int facc[BSZ * LDSPAD];   // 33.8 KB
    for (int i = threadIdx.x; i < BSZ * LDSPAD; i += 512) facc[i] = 0;
    __syncthreads();
    const int b = blockIdx.x;
    const int base = bucket_base[b];            // multiple of 4
    const int end = gcur[b];
    const int sl = threadIdx.x & 15;
    const int grp = threadIdx.x >> 4;           // 32 groups of 16 lanes

#define GA(cc) xws[(size_t)((cc) & 0x3FFFFu) * 16 + sl]
#define ACC_EDGE(cc, ww) do {                                                \
        float2 f_ = __half22float2(ww);                                      \
        int r_ = (int)((cc) >> 18) * LDSPAD + sl;                            \
        atomicAdd(&facc[r_],      __float2int_rn(f_.x * FXS));               \
        atomicAdd(&facc[r_ + 16], __float2int_rn(f_.y * FXS));               \
    } while (0)

    const int t0 = base + ((end - base) & ~15);
    for (int e = base + grp * 16; e < t0; e += 32 * 16) {
        uint4 c0 = *(const uint4*)(codes + e);
        uint4 c1 = *(const uint4*)(codes + e + 4);
        uint4 c2 = *(const uint4*)(codes + e + 8);
        uint4 c3 = *(const uint4*)(codes + e + 12);
        __half2 w0 = GA(c0.x), w1 = GA(c0.y), w2 = GA(c0.z), w3 = GA(c0.w);
        __half2 w4 = GA(c1.x), w5 = GA(c1.y), w6 = GA(c1.z), w7 = GA(c1.w);
        __half2 w8 = GA(c2.x), w9 = GA(c2.y), wA = GA(c2.z), wB = GA(c2.w);
        __half2 wC = GA(c3.x), wD = GA(c3.y), wE = GA(c3.z), wF = GA(c3.w);
        ACC_EDGE(c0.x, w0); ACC_EDGE(c0.y, w1); ACC_EDGE(c0.z, w2); ACC_EDGE(c0.w, w3);
        ACC_EDGE(c1.x, w4); ACC_EDGE(c1.y, w5); ACC_EDGE(c1.z, w6); ACC_EDGE(c1.w, w7);
        ACC_EDGE(c2.x, w8); ACC_EDGE(c2.y, w9); ACC_EDGE(c2.z, wA); ACC_EDGE(c2.w, wB);
        ACC_EDGE(c3.x, wC); ACC_EDGE(c3.y, wD); ACC_EDGE(c3.z, wE); ACC_EDGE(c3.w, wF);
    }
    for (int e = t0 + grp; e < end; e += 32) {
        unsigned c = codes[e];
        __half2 w = GA(c);
        ACC_EDGE(c, w);
    }
#undef ACC_EDGE
#undef GA

    __syncthreads();
    const float bn0 = b_n[2 * sl], bn1 = b_n[2 * sl + 1];
    const float bs0 = b_s[2 * sl], bs1 = b_s[2 * sl + 1];
    const float wl0 = W_lin[2 * sl], wl1 = W_lin[2 * sl + 1];
    const float bl  = b_lin[0];
    for (int p = grp; p < 128; p += 32) {
        int node = b * 128 + p;
        if (node >= N) break;
        int rn = (2 * p) * LDSPAD, rs = rn + LDSPAD;
        float anx = (float)facc[rn + sl] * FXSI, any_ = (float)facc[rn + 16 + sl] * FXSI;
        float asx = (float)facc[rs + sl] * FXSI, asy  = (float)facc[rs + 16 + sl] * FXSI;
        float2 ns = __half22float2(xws[(size_t)(2 * node) * 16 + sl]);
        float2 ss = __half22float2(xws[(size_t)(2 * node + 1) * 16 + sl]);
        float dn  = rsqrtf((float)cnt[2 * node] + 1.0f);
        float dsv = rsqrtf((float)cnt[2 * node + 1] + 1.0f);
        float h0 = (anx + ns.x) * dn + bn0 + (asx + ss.x) * dsv + bs0;
        float h1 = (any_ + ns.y) * dn + bn1 + (asy + ss.y) * dsv + bs1;
        float pr = fmaxf(h0, 0.f) * wl0 + fmaxf(h1, 0.f) * wl1;
#pragma unroll
        for (int off = 8; off > 0; off >>= 1) pr += __shfl_xor(pr, off, 16);
        if (sl == 0) out[node] = pr + bl;
    }
}

extern "C" void kernel_launch(void* const* d_in, const int* in_sizes, int n_in,
                              void* d_out, int out_size, void* d_ws, size_t ws_size,
                              hipStream_t stream) {
    const float* x     = (const float*)d_in[0];
    const int*   ei_n  = (const int*)d_in[1];
    const int*   ei_s  = (const int*)d_in[2];
    const float* W_n   = (const float*)d_in[3];
    const float* b_n   = (const float*)d_in[4];
    const float* W_s   = (const float*)d_in[5];
    const float* b_s   = (const float*)d_in[6];
    const float* W_lin = (const float*)d_in[7];
    const float* b_lin = (const float*)d_in[8];
    float* out = (float*)d_out;

    const int N  = in_sizes[0] / 64;   // 100000
    const int En = in_sizes[1] / 2;    // 3200000
    const int Es = in_sizes[2] / 2;    // 3200000
    const int M  = 2 * N;              // 200000 vnodes (vn = 2*node + type)
    const int nb = (M + BSZ - 1) / BSZ;            // 782 buckets
    const size_t Etot = (size_t)En + (size_t)Es;   // 6.4M

    // Workspace (~40 MB): btot[nb] | bucket_base[nb] | gcur[nb] | cnt[M]
    // | codes[Etot + 4*nb] (16B aligned) | xws[16*M half2]
    int* btot        = (int*)d_ws;
    int* bucket_base = btot + nb;
    int* gcur        = bucket_base + nb;
    int* cnt         = gcur + nb;
    uintptr_t pcodes = (uintptr_t)(cnt + M);
    pcodes = (pcodes + 15) & ~(uintptr_t)15;
    unsigned int* codes = (unsigned int*)pcodes;
    __half2* xws = (__half2*)(codes + Etot + 4 * (size_t)nb);

    hipMemsetAsync(btot, 0, (size_t)nb * sizeof(int), stream);

    bhist_kernel<<<dim3(SLICES, 2), 256, 0, stream>>>(ei_n, ei_s, btot, N, En, Es, nb);
    scan_kernel<<<1, 1024, 0, stream>>>(btot, bucket_base, gcur, nb);
    place_kernel<<<dim3(SLICES, 2), 512, 0, stream>>>(ei_n, ei_s, gcur, codes,
                                                      N, En, Es, nb);
    dcount_kernel<<<nb, 256, 0, stream>>>(codes, bucket_base, gcur, cnt, M);
    xw_kernel<<<(N + 255) / 256, 256, 0, stream>>>(x, W_n, W_s, cnt, xws, N);
    gather_kernel<<<nb, 512, 0, stream>>>(codes, bucket_base, gcur, xws, cnt,
                                          b_n, b_s, W_lin, b_lin, out, N);
}